// Round 9
// baseline (323.676 us; speedup 1.0000x reference)
//
#include <hip/hip_runtime.h>
#include <hip/hip_cooperative_groups.h>
#include <math.h>

namespace cg = cooperative_groups;

#define VOCABN 100000
#define EMBD 300
#define HID 128
#define NQ 32
#define NTOP 10

#define NCHS 19             // chunks scored (k 0..303; chunks hold 16 k each)
#define NCHT 20             // chunks in W table (last is zero-pad)
#define CMIN 3
#define CAPA 43712
#define NTHR 256

typedef __attribute__((ext_vector_type(8))) short bf16x8;
typedef __attribute__((ext_vector_type(4))) float f32x4;
typedef __attribute__((ext_vector_type(16))) float f32x16;
typedef __attribute__((ext_vector_type(4))) unsigned int u32x4;

__device__ __forceinline__ void split8(const f32x4 a, const f32x4 b,
                                       u32x4* hi, u32x4* lo) {
    float ef[8] = {a.x, a.y, a.z, a.w, b.x, b.y, b.z, b.w};
    unsigned int hw[8], lw[8];
#pragma unroll
    for (int j = 0; j < 8; ++j) {
        unsigned int u = __float_as_uint(ef[j]);
        hw[j] = u >> 16;
        float r = __uint_as_float(u & 0xffff0000u);
        lw[j] = __float_as_uint(ef[j] - r) >> 16;
    }
    *hi = (u32x4){hw[0] | (hw[1] << 16), hw[2] | (hw[3] << 16),
                  hw[4] | (hw[5] << 16), hw[6] | (hw[7] << 16)};
    *lo = (u32x4){lw[0] | (lw[1] << 16), lw[2] | (lw[3] << 16),
                  lw[4] | (lw[5] << 16), lw[6] | (lw[7] << 16)};
}

__device__ __forceinline__ bool tbetter(float w1, int i1, float w2, int i2) {
    return w1 > w2 || (w1 == w2 && i1 < i2);
}

__device__ __forceinline__ void lds_insert(float* mw, int* mid, int t, float w, int id) {
    const int b = t * NTOP;
    if (!tbetter(w, id, mw[b + NTOP - 1], mid[b + NTOP - 1])) return;
    int p = NTOP - 1;
    while (p > 0 && tbetter(w, id, mw[b + p - 1], mid[b + p - 1])) {
        mw[b + p] = mw[b + p - 1]; mid[b + p] = mid[b + p - 1]; --p;
    }
    mw[b + p] = w; mid[b + p] = id;
}

// per-wave 32-row x 128-col bf16x3 MFMA scorer, tile-strided; depth-2 pipeline
__device__ void score_tiles(int gw, int nwaves, const float* __restrict__ emb,
                            const unsigned short* __restrict__ wfH,
                            const unsigned short* __restrict__ wfL,
                            const float* __restrict__ qcbp,
                            const float* __restrict__ w2p, float b2,
                            const int* __restrict__ cand,
                            const int* __restrict__ ccnt,
                            const int* __restrict__ counts, int ncand,
                            float* __restrict__ taw, int* __restrict__ tai,
                            float* pvrow) {
    const int lane = threadIdx.x & 63;
    const int lrow = lane & 31;
    const int khalf = lane >> 5;
    const int ntile = (ncand + 31) >> 5;

    float qv[4], w2v[4];
#pragma unroll
    for (int t = 0; t < 4; ++t) {
        qv[t] = qcbp[t * 32 + lrow];
        w2v[t] = w2p[t * 32 + lrow];
    }

    for (int tile = gw; tile < ntile; tile += nwaves) {
        const int base = tile * 32;
        int ri = base + lrow;
        int rc = ri < ncand ? ri : ncand - 1;
        const long row = cand ? (long)cand[rc] : (long)rc;
        const float* ebase = emb + row * EMBD;

        f32x16 acc[4];
#pragma unroll
        for (int t = 0; t < 4; ++t)
#pragma unroll
            for (int r = 0; r < 16; ++r) acc[t][r] = 0.f;

        f32x4 e0[2], e1[2];
        u32x4 wh[2][4], wl[2][4];
        const f32x4 zf4 = (f32x4){0.f, 0.f, 0.f, 0.f};

#define LOADC(NN, S)                                                         \
    { int nn_ = (NN);                                                        \
      if (nn_ < NCHS) {                                                      \
          int k0_ = nn_ * 16 + khalf * 8;                                    \
          e0[S] = (k0_ + 4 <= EMBD) ? *(const f32x4*)(ebase + k0_) : zf4;    \
          e1[S] = (k0_ + 8 <= EMBD) ? *(const f32x4*)(ebase + k0_ + 4) : zf4;\
          _Pragma("unroll")                                                  \
          for (int t_ = 0; t_ < 4; ++t_) {                                   \
              long fo_ = ((long)(nn_ * 4 + t_) * 64 + lane) * 8;             \
              wh[S][t_] = *(const u32x4*)&wfH[fo_];                          \
              wl[S][t_] = *(const u32x4*)&wfL[fo_];                          \
          } } }

#define COMP(CC, S)                                                          \
    { if ((CC) < NCHS) {                                                     \
          union { bf16x8 v; u32x4 u; } eh_, el_;                             \
          split8(e0[S], e1[S], &eh_.u, &el_.u);                              \
          _Pragma("unroll")                                                  \
          for (int t_ = 0; t_ < 4; ++t_) {                                   \
              union { bf16x8 v; u32x4 u; } bh_, bl_;                         \
              bh_.u = wh[S][t_]; bl_.u = wl[S][t_];                          \
              acc[t_] = __builtin_amdgcn_mfma_f32_32x32x16_bf16(eh_.v, bh_.v, acc[t_], 0, 0, 0); \
              acc[t_] = __builtin_amdgcn_mfma_f32_32x32x16_bf16(eh_.v, bl_.v, acc[t_], 0, 0, 0); \
              acc[t_] = __builtin_amdgcn_mfma_f32_32x32x16_bf16(el_.v, bh_.v, acc[t_], 0, 0, 0); \
          } } }

        LOADC(0, 0) LOADC(1, 1)
#pragma unroll
        for (int g = 0; g < 10; ++g) {
            const int c = g * 2;
            COMP(c + 0, 0) LOADC(c + 2, 0)
            COMP(c + 1, 1) LOADC(c + 3, 1)
        }
#undef LOADC
#undef COMP

        float pr[16];
#pragma unroll
        for (int r = 0; r < 16; ++r) {
            float s = 0.f;
#pragma unroll
            for (int t = 0; t < 4; ++t) {
                float h = fmaxf(acc[t][r] + qv[t], 0.f);
                s += h * w2v[t];
            }
            s += __shfl_xor(s, 1); s += __shfl_xor(s, 2);
            s += __shfl_xor(s, 4); s += __shfl_xor(s, 8);
            s += __shfl_xor(s, 16);
            pr[r] = s;
        }
        if (lrow == 0) {
#pragma unroll
            for (int r = 0; r < 16; ++r)
                pvrow[(r & 3) + 8 * (r >> 2) + 4 * khalf] = pr[r];
        }
        asm volatile("s_waitcnt lgkmcnt(0)" ::: "memory");
        __builtin_amdgcn_sched_barrier(0);

        int gidx = base + lrow;
        float w = -1.f; int id = 0x7fffffff;
        if (gidx < ncand) {
            id = cand ? cand[gidx] : gidx;
            int cnt = cand ? ccnt[gidx] : counts[gidx];
            w = (float)cnt / (1.f + expf(-(pvrow[lrow] + b2)));
        }
        for (int r = 0; r < NTOP; ++r) {
            float bw = w; int bid = id;
#pragma unroll
            for (int m = 1; m < 32; m <<= 1) {
                float ow = __shfl_xor(bw, m); int oid = __shfl_xor(bid, m);
                if (ow > bw || (ow == bw && oid < bid)) { bw = ow; bid = oid; }
            }
            if (w == bw && id == bid) w = -2.f;
            if (lane == r) { taw[tile * NTOP + r] = bw; tai[tile * NTOP + r] = bid; }
        }
    }
}

__global__ void __launch_bounds__(NTHR, 2)
k_mega(const int* __restrict__ qterms, const int* __restrict__ fdocs, int nflat,
       const float* __restrict__ emb, const float* __restrict__ sW1,
       const float* __restrict__ sb1, const float* __restrict__ sW2,
       const float* __restrict__ sb2, const float* __restrict__ eW1,
       const float* __restrict__ eb1, const float* __restrict__ eW2,
       const float* __restrict__ eb2, char* __restrict__ ws,
       float* __restrict__ out) {
    cg::grid_group gridg = cg::this_grid();

    int* counts = (int*)ws;                                   // 400000 B
    int* ncA    = (int*)(ws + 400000);                        // 4
    float* qctx = (float*)(ws + 400064);                      // 1200
    float* qcb  = (float*)(ws + 401280);                      // 512
    int* flagp  = (int*)(ws + 401792);                        // 4
    unsigned short* wfH = (unsigned short*)(ws + 401920);     // 81920
    unsigned short* wfL = (unsigned short*)(ws + 483840);     // 81920
    int* candA  = (int*)(ws + 565760);                        // 174848
    int* ccntA  = (int*)(ws + 740608);                        // 174848
    float* tawA = (float*)(ws + 915456);                      // 54640
    int*   taiA = (int*)(ws + 970096);                        // 54640
    float* tawB = (float*)(ws + 1024736);                     // 125000
    int*   taiB = (int*)(ws + 1149736);                       // 125000 -> 1274736 total

    const int t = threadIdx.x;
    const int b = blockIdx.x;
    const int nb = gridDim.x;
    const int gid = b * NTHR + t;
    const int gstride = nb * NTHR;
    const int gw = b * 4 + (t >> 6);
    const int nwaves = nb * 4;

    __shared__ float mw[NTHR * NTOP];
    __shared__ int   mid[NTHR * NTOP];
    __shared__ float pvs[4][32];
    __shared__ float qc[EMBD], em[EMBD], hbuf[HID];
    __shared__ int   qid[NQ];
    __shared__ float atw[NTOP];
    __shared__ int   ati[NTOP];
    __shared__ int   top_id[NTOP];

    // ---------- Phase A: zero counts+ncA | W bf16 fragment table | qctx+qcb ----------
    for (int i = gid; i < VOCABN + 1; i += gstride) ((int*)ws)[i] = 0;
    if (gid < NCHT * 4 * 64) {   // 5120 fragment builders
        int c = gid >> 8;
        int rest = gid & 255;
        int tile = rest >> 6;
        int l = rest & 63;
        int col = tile * 32 + (l & 31);
        int kbase = c * 16 + (l >> 5) * 8;
        unsigned int hw[8], lw[8];
#pragma unroll
        for (int j = 0; j < 8; ++j) {
            int k = kbase + j;
            unsigned int hi = 0, lo = 0;
            if (k < EMBD) {
                float f = sW1[(long)k * HID + col];
                unsigned int u = __float_as_uint(f);
                hi = u >> 16;
                float r = __uint_as_float(u & 0xffff0000u);
                lo = __float_as_uint(f - r) >> 16;
            }
            hw[j] = hi; lw[j] = lo;
        }
        long fo = ((long)(c * 4 + tile) * 64 + l) * 8;
        *(u32x4*)&wfH[fo] = (u32x4){hw[0] | (hw[1] << 16), hw[2] | (hw[3] << 16),
                                    hw[4] | (hw[5] << 16), hw[6] | (hw[7] << 16)};
        *(u32x4*)&wfL[fo] = (u32x4){lw[0] | (lw[1] << 16), lw[2] | (lw[3] << 16),
                                    lw[4] | (lw[5] << 16), lw[6] | (lw[7] << 16)};
    }
    if (b == nb - 1) {
        if (t < NQ) qid[t] = qterms[t];
        __syncthreads();
        for (int i = t; i < EMBD; i += NTHR) {
            float s = 0.f;
            for (int q = 0; q < NQ; ++q) s += emb[(long)qid[q] * EMBD + i];
            float v = s * (1.0f / NQ);
            qc[i] = v; qctx[i] = v;
        }
        __syncthreads();
        int col = t >> 1, half = t & 1;
        float a = 0.f;
        int k0 = half * 150;
        for (int k = k0; k < k0 + 150; ++k)
            a += qc[k] * sW1[(long)(EMBD + k) * HID + col];
        a += __shfl_xor(a, 1);
        if (half == 0) qcb[col] = a + sb1[col];
    }
    gridg.sync();

    // ---------- Phase B: histogram ----------
    for (int i = gid; i < nflat; i += gstride)
        atomicAdd(&counts[fdocs[i]], 1);
    gridg.sync();

    // ---------- Phase C: compact (count >= CMIN) ----------
    for (int i = gid; i < VOCABN; i += gstride) {
        int c = counts[i];
        if (c >= CMIN) {
            int p = atomicAdd(ncA, 1);
            if (p < CAPA) { candA[p] = i; ccntA[p] = c; }
        }
    }
    gridg.sync();

    // ---------- Phase D: score A-candidates ----------
    int nA = *(volatile int*)ncA; if (nA > CAPA) nA = CAPA;
    score_tiles(gw, nwaves, emb, wfH, wfL, qcb, sW2, sb2[0],
                candA, ccntA, nullptr, nA, tawA, taiA, pvs[t >> 6]);
    gridg.sync();

    // ---------- Phase E: merge A (block 0) + flag ----------
    if (b == 0) {
        int ntA = (nA + 31) >> 5;
#pragma unroll
        for (int n = 0; n < NTOP; ++n) { mw[t * NTOP + n] = -1.f; mid[t * NTOP + n] = 0x7fffffff; }
        for (int i = t; i < ntA * NTOP; i += NTHR)
            lds_insert(mw, mid, t, tawA[i], taiA[i]);
        for (int s = NTHR / 2; s > 0; s >>= 1) {
            __syncthreads();
            if (t < s) {
                const int ta = t * NTOP, tb = (t + s) * NTOP;
                float ow[NTOP]; int oid[NTOP];
                int i = 0, j = 0;
#pragma unroll
                for (int n = 0; n < NTOP; ++n) {
                    float wa = mw[ta + i]; int ia = mid[ta + i];
                    float wb = mw[tb + j]; int ib = mid[tb + j];
                    if (tbetter(wa, ia, wb, ib)) { ow[n] = wa; oid[n] = ia; ++i; }
                    else                         { ow[n] = wb; oid[n] = ib; ++j; }
                }
#pragma unroll
                for (int n = 0; n < NTOP; ++n) { mw[ta + n] = ow[n]; mid[ta + n] = oid[n]; }
            }
        }
        __syncthreads();
        if (t < NTOP) { atw[t] = mw[t]; ati[t] = mid[t]; }
        if (t == 0) *flagp = (mw[NTOP - 1] > (float)(CMIN - 1)) ? 1 : 0;
        __threadfence();
    }
    gridg.sync();

    // ---------- Phase F: conditional exact fallback (full vocab sweep) ----------
    const int flag = *(volatile int*)flagp;
    if (!flag)
        score_tiles(gw, nwaves, emb, wfH, wfL, qcb, sW2, sb2[0],
                    nullptr, nullptr, counts, VOCABN, tawB, taiB, pvs[t >> 6]);
    gridg.sync();

    // ---------- Phase G: final top-10 + expansion MLP (block 0) ----------
    if (b == 0) {
        if (flag) {
            if (t < NTOP) {
                top_id[t] = ati[t];
                out[EMBD + t] = (float)ati[t];
                out[EMBD + NTOP + t] = atw[t];
            }
        } else {
            const int ntB = (VOCABN + 31) >> 5;
#pragma unroll
            for (int n = 0; n < NTOP; ++n) { mw[t * NTOP + n] = -1.f; mid[t * NTOP + n] = 0x7fffffff; }
            for (int i = t; i < ntB * NTOP; i += NTHR)
                lds_insert(mw, mid, t, tawB[i], taiB[i]);
            for (int s = NTHR / 2; s > 0; s >>= 1) {
                __syncthreads();
                if (t < s) {
                    const int ta = t * NTOP, tb = (t + s) * NTOP;
                    float ow[NTOP]; int oid[NTOP];
                    int i = 0, j = 0;
#pragma unroll
                    for (int n = 0; n < NTOP; ++n) {
                        float wa = mw[ta + i]; int ia = mid[ta + i];
                        float wb = mw[tb + j]; int ib = mid[tb + j];
                        if (tbetter(wa, ia, wb, ib)) { ow[n] = wa; oid[n] = ia; ++i; }
                        else                         { ow[n] = wb; oid[n] = ib; ++j; }
                    }
#pragma unroll
                    for (int n = 0; n < NTOP; ++n) { mw[ta + n] = ow[n]; mid[ta + n] = oid[n]; }
                }
            }
            __syncthreads();
            if (t < NTOP) {
                top_id[t] = mid[t];
                out[EMBD + t] = (float)mid[t];
                out[EMBD + NTOP + t] = mw[t];
            }
        }
        __syncthreads();

        for (int i = t; i < EMBD; i += NTHR) {
            float s = 0.f;
            for (int n = 0; n < NTOP; ++n) {
                long rid = top_id[n];
                if (rid > VOCABN - 1) rid = VOCABN - 1;   // sentinel clamp
                s += emb[rid * EMBD + i];
            }
            em[i] = s * (1.0f / NTOP);
            qc[i] = qctx[i];
        }
        __syncthreads();

        {   // h = relu(feat . eW1 + eb1); 2 threads per col, K split 150
            int col = t >> 1, ks = t & 1;
            float a = 0.f;
            int k0 = ks * 150, k1 = k0 + 150;
            for (int k = k0; k < k1; ++k) {
                float q = qc[k], e = em[k];
                a += q * eW1[(long)k * HID + col];
                a += e * eW1[(long)(EMBD + k) * HID + col];
                a += (q * e) * eW1[(long)(2 * EMBD + k) * HID + col];
            }
            a += __shfl_xor(a, 1);
            if (ks == 0) hbuf[col] = fmaxf(a + eb1[col], 0.f);
        }
        __syncthreads();

        for (int i = t; i < EMBD; i += NTHR) {
            float a = eb2[i];
            for (int j = 0; j < HID; ++j) a += hbuf[j] * eW2[(long)j * EMBD + i];
            out[i] = a;
        }
    }
}

extern "C" void kernel_launch(void* const* d_in, const int* in_sizes, int n_in,
                              void* d_out, int out_size, void* d_ws, size_t ws_size,
                              hipStream_t stream) {
    const int* qterms  = (const int*)d_in[0];
    const int* fdocs   = (const int*)d_in[1];
    const float* emb   = (const float*)d_in[3];
    const float* sW1   = (const float*)d_in[4];
    const float* sb1   = (const float*)d_in[5];
    const float* sW2   = (const float*)d_in[6];
    const float* sb2   = (const float*)d_in[7];
    const float* eW1   = (const float*)d_in[8];
    const float* eb1   = (const float*)d_in[9];
    const float* eW2   = (const float*)d_in[10];
    const float* eb2   = (const float*)d_in[11];
    char* ws = (char*)d_ws;
    float* out = (float*)d_out;

    int nflat = in_sizes[1];

    void* kargs[] = {
        (void*)&qterms, (void*)&fdocs, (void*)&nflat, (void*)&emb,
        (void*)&sW1, (void*)&sb1, (void*)&sW2, (void*)&sb2,
        (void*)&eW1, (void*)&eb1, (void*)&eW2, (void*)&eb2,
        (void*)&ws, (void*)&out
    };

    // size grid from the runtime's own occupancy math (same check the
    // cooperative-launch validator applies), then verify the launch result.
    int maxPerCU = 0;
    hipError_t qe = hipOccupancyMaxActiveBlocksPerMultiprocessor(
        &maxPerCU, (const void*)k_mega, NTHR, 0);
    if (qe != hipSuccess || maxPerCU < 1) maxPerCU = 1;
    int grid = 256;
    long cap = (long)maxPerCU * 256;
    if (grid > cap) grid = (int)cap;
    if (grid < 32) grid = 32;

    hipError_t e = hipLaunchCooperativeKernel((const void*)k_mega, dim3(grid),
                                              dim3(NTHR), kargs, 0, stream);
    if (e != hipSuccess && grid > 128) {
        grid = 128;
        e = hipLaunchCooperativeKernel((const void*)k_mega, dim3(grid),
                                       dim3(NTHR), kargs, 0, stream);
    }
    if (e != hipSuccess && grid > 64) {
        grid = 64;
        (void)hipLaunchCooperativeKernel((const void*)k_mega, dim3(grid),
                                         dim3(NTHR), kargs, 0, stream);
    }
}

// Round 11
// 157.060 us; speedup vs baseline: 2.0608x; 2.0608x over previous
//
#include <hip/hip_runtime.h>
#include <math.h>

#define VOCABN 100000
#define EMBD 300
#define HID 128
#define NQ 32
#define NTOP 10

#define NCHS 19             // chunks scored, 16 k each (k 0..303, tail zero-padded)
#define NCHT 20             // chunks in W fragment table
#define GRID_S ((VOCABN + 31) / 32)   // 3125 one-wave score blocks

typedef __attribute__((ext_vector_type(8))) short bf16x8;
typedef __attribute__((ext_vector_type(4))) float f32x4;
typedef __attribute__((ext_vector_type(16))) float f32x16;
typedef __attribute__((ext_vector_type(4))) unsigned int u32x4;

__device__ __forceinline__ void split8(const f32x4 a, const f32x4 b,
                                       u32x4* hi, u32x4* lo) {
    float ef[8] = {a.x, a.y, a.z, a.w, b.x, b.y, b.z, b.w};
    unsigned int hw[8], lw[8];
#pragma unroll
    for (int j = 0; j < 8; ++j) {
        unsigned int u = __float_as_uint(ef[j]);
        hw[j] = u >> 16;
        float r = __uint_as_float(u & 0xffff0000u);
        lw[j] = __float_as_uint(ef[j] - r) >> 16;
    }
    *hi = (u32x4){hw[0] | (hw[1] << 16), hw[2] | (hw[3] << 16),
                  hw[4] | (hw[5] << 16), hw[6] | (hw[7] << 16)};
    *lo = (u32x4){lw[0] | (lw[1] << 16), lw[2] | (lw[3] << 16),
                  lw[4] | (lw[5] << 16), lw[6] | (lw[7] << 16)};
}

__device__ __forceinline__ bool tbetter(float w1, int i1, float w2, int i2) {
    return w1 > w2 || (w1 == w2 && i1 < i2);
}

__device__ __forceinline__ void lds_insert(float* mw, int* mid, int t, float w, int id) {
    const int b = t * NTOP;
    if (!tbetter(w, id, mw[b + NTOP - 1], mid[b + NTOP - 1])) return;
    int p = NTOP - 1;
    while (p > 0 && tbetter(w, id, mw[b + p - 1], mid[b + p - 1])) {
        mw[b + p] = mw[b + p - 1]; mid[b + p] = mid[b + p - 1]; --p;
    }
    mw[b + p] = w; mid[b + p] = id;
}

// ---------------- zero the histogram (replaces the 69us rocclr fill) ----------------
__global__ __launch_bounds__(256) void k_zero(int* __restrict__ counts) {
    int i = blockIdx.x * 256 + threadIdx.x;
    if (i < VOCABN) counts[i] = 0;
}

// ---------- fused: histogram | qctx+qcb | W1a -> fragment-major bf16 hi/lo ----------
__global__ __launch_bounds__(256) void k_pre(const int* __restrict__ qterms,
                                             const int* __restrict__ fdocs, int nflat, int hblocks,
                                             const float* __restrict__ emb,
                                             const float* __restrict__ sW1,
                                             const float* __restrict__ sb1,
                                             int* __restrict__ counts,
                                             float* __restrict__ qctx,
                                             float* __restrict__ qcb,
                                             unsigned short* __restrict__ wfH,
                                             unsigned short* __restrict__ wfL) {
    int t = threadIdx.x;
    int b = blockIdx.x;
    if (b < hblocks) {                       // histogram
        int i = b * 256 + t;
        if (i < nflat) atomicAdd(&counts[fdocs[i]], 1);
        return;
    }
    if (b == hblocks) {                      // query context + scorer bias
        __shared__ int qid[NQ];
        __shared__ float qc[EMBD];
        if (t < NQ) qid[t] = qterms[t];
        __syncthreads();
        for (int i = t; i < EMBD; i += 256) {
            float s = 0.f;
            for (int q = 0; q < NQ; ++q) s += emb[(long)qid[q] * EMBD + i];
            float v = s * (1.0f / NQ);
            qc[i] = v; qctx[i] = v;
        }
        __syncthreads();
        int col = t >> 1, half = t & 1;
        float a = 0.f;
        int k0 = half * 150;
        for (int k = k0; k < k0 + 150; ++k)
            a += qc[k] * sW1[(long)(EMBD + k) * HID + col];
        a += __shfl_xor(a, 1);
        if (half == 0) qcb[col] = a + sb1[col];
        return;
    }
    // W fragments: thread = (chunk c, tile, lane); 20 blocks x 256
    int i = (b - hblocks - 1) * 256 + t;
    int c = i >> 8;
    int rest = i & 255;
    int tile = rest >> 6;
    int l = rest & 63;
    int col = tile * 32 + (l & 31);
    int kbase = c * 16 + (l >> 5) * 8;
    unsigned int hw[8], lw[8];
#pragma unroll
    for (int j = 0; j < 8; ++j) {
        int k = kbase + j;
        unsigned int hi = 0, lo = 0;
        if (k < EMBD) {
            float f = sW1[(long)k * HID + col];
            unsigned int u = __float_as_uint(f);
            hi = u >> 16;
            float r = __uint_as_float(u & 0xffff0000u);
            lo = __float_as_uint(f - r) >> 16;
        }
        hw[j] = hi; lw[j] = lo;
    }
    long fo = ((long)(c * 4 + tile) * 64 + l) * 8;
    *(u32x4*)&wfH[fo] = (u32x4){hw[0] | (hw[1] << 16), hw[2] | (hw[3] << 16),
                                hw[4] | (hw[5] << 16), hw[6] | (hw[7] << 16)};
    *(u32x4*)&wfL[fo] = (u32x4){lw[0] | (lw[1] << 16), lw[2] | (lw[3] << 16),
                                lw[4] | (lw[5] << 16), lw[6] | (lw[7] << 16)};
}

// ---------- barrier-free 1-wave scorer: 32 dense rows, 128 cols, bf16x3 MFMA ----------
// weight[v] = counts[v] * sigmoid(W2 . relu(emb[v].W1a + qcb) + b2); per-block top-10.
// C/D: col = lane&31 (HID dim), row = (r&3) + 8*(r>>2) + 4*(lane>>5)
__global__ __launch_bounds__(64) void k_score(
        const float* __restrict__ emb,
        const unsigned short* __restrict__ wfH,
        const unsigned short* __restrict__ wfL,
        const float* __restrict__ qcb,
        const float* __restrict__ sW2,
        const float* __restrict__ sb2,
        const int* __restrict__ counts,
        float* __restrict__ taw, int* __restrict__ tai) {
    const int lane = threadIdx.x;
    const int blk = blockIdx.x;
    const int base = blk * 32;
    const int lrow = lane & 31;
    const int khalf = lane >> 5;

    const float* ebase = emb + (long)(base + lrow) * EMBD;

    f32x16 acc[4];
#pragma unroll
    for (int t = 0; t < 4; ++t)
#pragma unroll
        for (int r = 0; r < 16; ++r) acc[t][r] = 0.f;

    f32x4 e0[2], e1[2];
    u32x4 wh[2][4], wl[2][4];
    const f32x4 zf4 = (f32x4){0.f, 0.f, 0.f, 0.f};

#define LOADC(NN, S)                                                         \
    { int nn_ = (NN);                                                        \
      if (nn_ < NCHS) {                                                      \
          int k0_ = nn_ * 16 + khalf * 8;                                    \
          e0[S] = (k0_ + 4 <= EMBD) ? *(const f32x4*)(ebase + k0_) : zf4;    \
          e1[S] = (k0_ + 8 <= EMBD) ? *(const f32x4*)(ebase + k0_ + 4) : zf4;\
          _Pragma("unroll")                                                  \
          for (int t_ = 0; t_ < 4; ++t_) {                                   \
              long fo_ = ((long)(nn_ * 4 + t_) * 64 + lane) * 8;             \
              wh[S][t_] = *(const u32x4*)&wfH[fo_];                          \
              wl[S][t_] = *(const u32x4*)&wfL[fo_];                          \
          } } }

#define COMP(CC, S)                                                          \
    { if ((CC) < NCHS) {                                                     \
          union { bf16x8 v; u32x4 u; } eh_, el_;                             \
          split8(e0[S], e1[S], &eh_.u, &el_.u);                              \
          _Pragma("unroll")                                                  \
          for (int t_ = 0; t_ < 4; ++t_) {                                   \
              union { bf16x8 v; u32x4 u; } bh_, bl_;                         \
              bh_.u = wh[S][t_]; bl_.u = wl[S][t_];                          \
              acc[t_] = __builtin_amdgcn_mfma_f32_32x32x16_bf16(eh_.v, bh_.v, acc[t_], 0, 0, 0); \
              acc[t_] = __builtin_amdgcn_mfma_f32_32x32x16_bf16(eh_.v, bl_.v, acc[t_], 0, 0, 0); \
              acc[t_] = __builtin_amdgcn_mfma_f32_32x32x16_bf16(el_.v, bh_.v, acc[t_], 0, 0, 0); \
          } } }

    LOADC(0, 0) LOADC(1, 1)
#pragma unroll
    for (int g = 0; g < 10; ++g) {
        const int c = g * 2;
        COMP(c + 0, 0) LOADC(c + 2, 0)
        COMP(c + 1, 1) LOADC(c + 3, 1)
    }
#undef LOADC
#undef COMP

    // epilogue: relu + W2 dot + 32-lane column reduce
    float qv[4], w2v[4];
#pragma unroll
    for (int t = 0; t < 4; ++t) {
        qv[t] = qcb[t * 32 + lrow];
        w2v[t] = sW2[t * 32 + lrow];
    }
    __shared__ float pv[32];
    float pr[16];
#pragma unroll
    for (int r = 0; r < 16; ++r) {
        float s = 0.f;
#pragma unroll
        for (int t = 0; t < 4; ++t) {
            float h = fmaxf(acc[t][r] + qv[t], 0.f);
            s += h * w2v[t];
        }
        s += __shfl_xor(s, 1); s += __shfl_xor(s, 2);
        s += __shfl_xor(s, 4); s += __shfl_xor(s, 8);
        s += __shfl_xor(s, 16);
        pr[r] = s;
    }
    if (lrow == 0) {
#pragma unroll
        for (int r = 0; r < 16; ++r)
            pv[(r & 3) + 8 * (r >> 2) + 4 * khalf] = pr[r];
    }
    asm volatile("s_waitcnt lgkmcnt(0)" ::: "memory");
    __builtin_amdgcn_sched_barrier(0);

    // weights + in-wave top-10 (both lane halves hold identical copies)
    const float b2 = sb2[0];
    int gidx = base + lrow;
    int id = gidx;
    float w = (float)counts[gidx] / (1.f + expf(-(pv[lrow] + b2)));
    for (int r = 0; r < NTOP; ++r) {
        float bw = w; int bid = id;
#pragma unroll
        for (int m = 1; m < 32; m <<= 1) {
            float ow = __shfl_xor(bw, m); int oid = __shfl_xor(bid, m);
            if (ow > bw || (ow == bw && oid < bid)) { bw = ow; bid = oid; }
        }
        if (w == bw && id == bid) w = -2.f;
        if (lane == r) { taw[blk * NTOP + r] = bw; tai[blk * NTOP + r] = bid; }
    }
}

// ---------- final: global top-10 merge + expansion MLP ----------
__global__ __launch_bounds__(512) void k_final(const float* __restrict__ taw,
                                               const int* __restrict__ tai,
                                               const float* __restrict__ qctx,
                                               const float* __restrict__ emb,
                                               const float* __restrict__ eW1,
                                               const float* __restrict__ eb1,
                                               const float* __restrict__ eW2,
                                               const float* __restrict__ eb2,
                                               float* __restrict__ out) {
    __shared__ float mw[512 * NTOP];   // 20 KB
    __shared__ int   mid[512 * NTOP];  // 20 KB
    __shared__ int   top_id[NTOP];
    __shared__ float qc[EMBD], em[EMBD], hbuf[HID];
    int t = threadIdx.x;
#pragma unroll
    for (int n = 0; n < NTOP; ++n) { mw[t * NTOP + n] = -1.f; mid[t * NTOP + n] = 0x7fffffff; }
    for (int i = t; i < GRID_S * NTOP; i += 512)
        lds_insert(mw, mid, t, taw[i], tai[i]);

    for (int s = 256; s > 0; s >>= 1) {
        __syncthreads();
        if (t < s) {
            const int ta = t * NTOP, tb = (t + s) * NTOP;
            float ow[NTOP]; int oid[NTOP];
            int i = 0, j = 0;
#pragma unroll
            for (int n = 0; n < NTOP; ++n) {
                float wa = mw[ta + i]; int ia = mid[ta + i];
                float wb = mw[tb + j]; int ib = mid[tb + j];
                if (tbetter(wa, ia, wb, ib)) { ow[n] = wa; oid[n] = ia; ++i; }
                else                         { ow[n] = wb; oid[n] = ib; ++j; }
            }
#pragma unroll
            for (int n = 0; n < NTOP; ++n) { mw[ta + n] = ow[n]; mid[ta + n] = oid[n]; }
        }
    }
    __syncthreads();

    if (t < NTOP) {
        top_id[t] = mid[t];
        out[EMBD + t] = (float)mid[t];
        out[EMBD + NTOP + t] = mw[t];
    }
    __syncthreads();

    for (int i = t; i < EMBD; i += 512) {
        float s = 0.f;
        for (int n = 0; n < NTOP; ++n) s += emb[(long)top_id[n] * EMBD + i];
        em[i] = s * (1.0f / NTOP);
        qc[i] = qctx[i];
    }
    __syncthreads();

    {   // h = relu(feat . eW1 + eb1); 4 threads per col, K split 75
        int col = t >> 2, ks = t & 3;
        float a = 0.f;
        int k0 = ks * 75, k1 = k0 + 75;
        for (int k = k0; k < k1; ++k) {
            float q = qc[k], e = em[k];
            a += q * eW1[(long)k * HID + col];
            a += e * eW1[(long)(EMBD + k) * HID + col];
            a += (q * e) * eW1[(long)(2 * EMBD + k) * HID + col];
        }
        a += __shfl_xor(a, 1);
        a += __shfl_xor(a, 2);
        if (ks == 0) hbuf[col] = fmaxf(a + eb1[col], 0.f);
    }
    __syncthreads();

    for (int i = t; i < EMBD; i += 512) {
        float a = eb2[i];
        for (int j = 0; j < HID; ++j) a += hbuf[j] * eW2[(long)j * EMBD + i];
        out[i] = a;
    }
}

extern "C" void kernel_launch(void* const* d_in, const int* in_sizes, int n_in,
                              void* d_out, int out_size, void* d_ws, size_t ws_size,
                              hipStream_t stream) {
    const int* qterms  = (const int*)d_in[0];
    const int* fdocs   = (const int*)d_in[1];
    const float* emb   = (const float*)d_in[3];
    const float* sW1   = (const float*)d_in[4];
    const float* sb1   = (const float*)d_in[5];
    const float* sW2   = (const float*)d_in[6];
    const float* sb2   = (const float*)d_in[7];
    const float* eW1   = (const float*)d_in[8];
    const float* eb1   = (const float*)d_in[9];
    const float* eW2   = (const float*)d_in[10];
    const float* eb2   = (const float*)d_in[11];
    float* out = (float*)d_out;

    char* ws = (char*)d_ws;
    int*   counts = (int*)ws;                             // 400000
    float* qctx   = (float*)(ws + 400000);                // 1200
    float* qcb    = (float*)(ws + 401216);                // 512
    unsigned short* wfH = (unsigned short*)(ws + 401728); // 81920
    unsigned short* wfL = (unsigned short*)(ws + 483648); // 81920
    float* taw    = (float*)(ws + 565568);                // 3125*10*4 = 125000
    int*   tai    = (int*)(ws + 690568);                  // 125000  -> 815568 total

    int nflat = in_sizes[1];
    int hblocks = (nflat + 255) / 256;     // 512

    k_zero<<<(VOCABN + 255) / 256, 256, 0, stream>>>(counts);
    k_pre<<<hblocks + 1 + NCHT, 256, 0, stream>>>(qterms, fdocs, nflat, hblocks,
                                                  emb, sW1, sb1, counts, qctx, qcb, wfH, wfL);
    k_score<<<GRID_S, 64, 0, stream>>>(emb, wfH, wfL, qcb, sW2, sb2, counts, taw, tai);
    k_final<<<1, 512, 0, stream>>>(taw, tai, qctx, emb, eW1, eb1, eW2, eb2, out);
}

// Round 12
// 106.990 us; speedup vs baseline: 3.0253x; 1.4680x over previous
//
#include <hip/hip_runtime.h>
#include <math.h>

#define VOCABN 100000
#define EMBD 300
#define HID 128
#define NQ 32
#define NTOP 10

#define NCHS 19             // chunks scored, 16 k each (k 0..303, tail zero-padded)
#define NCHT 20             // chunks in W fragment table
#define CMIN 3
#define CAPA 43691          // max candidates with count>=3 (131072/3)
#define GRID_A ((CAPA + 31) / 32)     // 1366
#define GRID_F ((VOCABN + 31) / 32)   // 3125

typedef __attribute__((ext_vector_type(8))) short bf16x8;
typedef __attribute__((ext_vector_type(4))) float f32x4;
typedef __attribute__((ext_vector_type(16))) float f32x16;
typedef __attribute__((ext_vector_type(4))) unsigned int u32x4;

__device__ __forceinline__ void split8(const f32x4 a, const f32x4 b,
                                       u32x4* hi, u32x4* lo) {
    float ef[8] = {a.x, a.y, a.z, a.w, b.x, b.y, b.z, b.w};
    unsigned int hw[8], lw[8];
#pragma unroll
    for (int j = 0; j < 8; ++j) {
        unsigned int u = __float_as_uint(ef[j]);
        hw[j] = u >> 16;
        float r = __uint_as_float(u & 0xffff0000u);
        lw[j] = __float_as_uint(ef[j] - r) >> 16;
    }
    *hi = (u32x4){hw[0] | (hw[1] << 16), hw[2] | (hw[3] << 16),
                  hw[4] | (hw[5] << 16), hw[6] | (hw[7] << 16)};
    *lo = (u32x4){lw[0] | (lw[1] << 16), lw[2] | (lw[3] << 16),
                  lw[4] | (lw[5] << 16), lw[6] | (lw[7] << 16)};
}

__device__ __forceinline__ bool tbetter(float w1, int i1, float w2, int i2) {
    return w1 > w2 || (w1 == w2 && i1 < i2);
}

__device__ __forceinline__ void lds_insert(float* mw, int* mid, int t, float w, int id) {
    const int b = t * NTOP;
    if (!tbetter(w, id, mw[b + NTOP - 1], mid[b + NTOP - 1])) return;
    int p = NTOP - 1;
    while (p > 0 && tbetter(w, id, mw[b + p - 1], mid[b + p - 1])) {
        mw[b + p] = mw[b + p - 1]; mid[b + p] = mid[b + p - 1]; --p;
    }
    mw[b + p] = w; mid[b + p] = id;
}

// ---------------- zero counts + ncand (replaces 69us rocclr fill) ----------------
__global__ __launch_bounds__(256) void k_zero(int* __restrict__ p) {
    int i = blockIdx.x * 256 + threadIdx.x;
    if (i < VOCABN + 1) p[i] = 0;   // counts[100000] slot = ncand (contiguous layout)
}

// ---------- fused: histogram | qctx+qcb | W1a -> fragment-major bf16 hi/lo ----------
__global__ __launch_bounds__(256) void k_pre(const int* __restrict__ qterms,
                                             const int* __restrict__ fdocs, int nflat, int hblocks,
                                             const float* __restrict__ emb,
                                             const float* __restrict__ sW1,
                                             const float* __restrict__ sb1,
                                             int* __restrict__ counts,
                                             float* __restrict__ qctx,
                                             float* __restrict__ qcb,
                                             unsigned short* __restrict__ wfH,
                                             unsigned short* __restrict__ wfL) {
    int t = threadIdx.x;
    int b = blockIdx.x;
    if (b < hblocks) {                       // histogram
        int i = b * 256 + t;
        if (i < nflat) atomicAdd(&counts[fdocs[i]], 1);
        return;
    }
    if (b == hblocks) {                      // query context + scorer bias
        __shared__ int qid[NQ];
        __shared__ float qc[EMBD];
        if (t < NQ) qid[t] = qterms[t];
        __syncthreads();
        for (int i = t; i < EMBD; i += 256) {
            float s = 0.f;
            for (int q = 0; q < NQ; ++q) s += emb[(long)qid[q] * EMBD + i];
            float v = s * (1.0f / NQ);
            qc[i] = v; qctx[i] = v;
        }
        __syncthreads();
        int col = t >> 1, half = t & 1;
        float a = 0.f;
        int k0 = half * 150;
        for (int k = k0; k < k0 + 150; ++k)
            a += qc[k] * sW1[(long)(EMBD + k) * HID + col];
        a += __shfl_xor(a, 1);
        if (half == 0) qcb[col] = a + sb1[col];
        return;
    }
    // W fragments: thread = (chunk c, tile, lane); 20 blocks x 256
    int i = (b - hblocks - 1) * 256 + t;
    int c = i >> 8;
    int rest = i & 255;
    int tile = rest >> 6;
    int l = rest & 63;
    int col = tile * 32 + (l & 31);
    int kbase = c * 16 + (l >> 5) * 8;
    unsigned int hw[8], lw[8];
#pragma unroll
    for (int j = 0; j < 8; ++j) {
        int k = kbase + j;
        unsigned int hi = 0, lo = 0;
        if (k < EMBD) {
            float f = sW1[(long)k * HID + col];
            unsigned int u = __float_as_uint(f);
            hi = u >> 16;
            float r = __uint_as_float(u & 0xffff0000u);
            lo = __float_as_uint(f - r) >> 16;
        }
        hw[j] = hi; lw[j] = lo;
    }
    long fo = ((long)(c * 4 + tile) * 64 + l) * 8;
    *(u32x4*)&wfH[fo] = (u32x4){hw[0] | (hw[1] << 16), hw[2] | (hw[3] << 16),
                                hw[4] | (hw[5] << 16), hw[6] | (hw[7] << 16)};
    *(u32x4*)&wfL[fo] = (u32x4){lw[0] | (lw[1] << 16), lw[2] | (lw[3] << 16),
                                lw[4] | (lw[5] << 16), lw[6] | (lw[7] << 16)};
}

// ---------- compact ids with count >= CMIN ----------
__global__ void k_compact(const int* __restrict__ counts, int* __restrict__ cand,
                          int* __restrict__ ccnt, int* __restrict__ ncand) {
    int i = blockIdx.x * blockDim.x + threadIdx.x;
    if (i < VOCABN) {
        int c = counts[i];
        if (c >= CMIN) {
            int p = atomicAdd(ncand, 1);
            if (p < CAPA) { cand[p] = i; ccnt[p] = c; }
        }
    }
}

// ---------- barrier-free 1-wave scorer: 32 rows, 128 cols, bf16x3 MFMA ----------
// C/D: col = lane&31 (HID dim), row = (r&3) + 8*(r>>2) + 4*(lane>>5)
__global__ __launch_bounds__(64) void k_score(
        const float* __restrict__ emb,
        const unsigned short* __restrict__ wfH,
        const unsigned short* __restrict__ wfL,
        const float* __restrict__ qcb,
        const float* __restrict__ sW2,
        const float* __restrict__ sb2,
        const int* __restrict__ counts,
        const int* __restrict__ cand,
        const int* __restrict__ ccnt,
        const int* __restrict__ ncand_p,
        const int* __restrict__ flagp,
        float* __restrict__ taw, int* __restrict__ tai) {
    if (flagp && *flagp != 0) return;        // fallback early-exit when pruning valid
    const int lane = threadIdx.x;
    const int blk = blockIdx.x;
    const int ncand = cand ? *ncand_p : VOCABN;
    const int base = blk * 32;
    if (base >= ncand) {
        if (lane < NTOP) { taw[blk * NTOP + lane] = -1.f; tai[blk * NTOP + lane] = 0x7fffffff; }
        return;
    }

    const int lrow = lane & 31;
    const int khalf = lane >> 5;

    int ri = base + lrow;
    int rc = ri < ncand ? ri : ncand - 1;
    const long row = cand ? (long)cand[rc] : (long)rc;
    const float* ebase = emb + row * EMBD;

    f32x16 acc[4];
#pragma unroll
    for (int t = 0; t < 4; ++t)
#pragma unroll
        for (int r = 0; r < 16; ++r) acc[t][r] = 0.f;

    f32x4 e0[3], e1[3];
    u32x4 wh[3][4], wl[3][4];
    const f32x4 zf4 = (f32x4){0.f, 0.f, 0.f, 0.f};

#define LOADC(NN, S)                                                         \
    { int nn_ = (NN);                                                        \
      if (nn_ < NCHS) {                                                      \
          int k0_ = nn_ * 16 + khalf * 8;                                    \
          e0[S] = (k0_ + 4 <= EMBD) ? *(const f32x4*)(ebase + k0_) : zf4;    \
          e1[S] = (k0_ + 8 <= EMBD) ? *(const f32x4*)(ebase + k0_ + 4) : zf4;\
          _Pragma("unroll")                                                  \
          for (int t_ = 0; t_ < 4; ++t_) {                                   \
              long fo_ = ((long)(nn_ * 4 + t_) * 64 + lane) * 8;             \
              wh[S][t_] = *(const u32x4*)&wfH[fo_];                          \
              wl[S][t_] = *(const u32x4*)&wfL[fo_];                          \
          } } }

#define COMP(CC, S)                                                          \
    { if ((CC) < NCHS) {                                                     \
          union { bf16x8 v; u32x4 u; } eh_, el_;                             \
          split8(e0[S], e1[S], &eh_.u, &el_.u);                              \
          _Pragma("unroll")                                                  \
          for (int t_ = 0; t_ < 4; ++t_) {                                   \
              union { bf16x8 v; u32x4 u; } bh_, bl_;                         \
              bh_.u = wh[S][t_]; bl_.u = wl[S][t_];                          \
              acc[t_] = __builtin_amdgcn_mfma_f32_32x32x16_bf16(eh_.v, bh_.v, acc[t_], 0, 0, 0); \
              acc[t_] = __builtin_amdgcn_mfma_f32_32x32x16_bf16(eh_.v, bl_.v, acc[t_], 0, 0, 0); \
              acc[t_] = __builtin_amdgcn_mfma_f32_32x32x16_bf16(el_.v, bh_.v, acc[t_], 0, 0, 0); \
          } } }

    LOADC(0, 0) LOADC(1, 1) LOADC(2, 2)
    for (int g = 0; g < 7; ++g) {
        int c = g * 3;
        COMP(c + 0, 0) LOADC(c + 3, 0)
        COMP(c + 1, 1) LOADC(c + 4, 1)
        COMP(c + 2, 2) LOADC(c + 5, 2)
    }
#undef LOADC
#undef COMP

    // epilogue: relu + W2 dot + 32-lane col reduce
    float qv[4], w2v[4];
#pragma unroll
    for (int t = 0; t < 4; ++t) {
        qv[t] = qcb[t * 32 + lrow];
        w2v[t] = sW2[t * 32 + lrow];
    }
    __shared__ float pv[32];
    float pr[16];
#pragma unroll
    for (int r = 0; r < 16; ++r) {
        float s = 0.f;
#pragma unroll
        for (int t = 0; t < 4; ++t) {
            float h = fmaxf(acc[t][r] + qv[t], 0.f);
            s += h * w2v[t];
        }
        s += __shfl_xor(s, 1); s += __shfl_xor(s, 2);
        s += __shfl_xor(s, 4); s += __shfl_xor(s, 8);
        s += __shfl_xor(s, 16);
        pr[r] = s;
    }
    if (lrow == 0) {
#pragma unroll
        for (int r = 0; r < 16; ++r)
            pv[(r & 3) + 8 * (r >> 2) + 4 * khalf] = pr[r];
    }
    asm volatile("s_waitcnt lgkmcnt(0)" ::: "memory");
    __builtin_amdgcn_sched_barrier(0);

    // weights + in-wave top-10 (both lane halves duplicate)
    const float b2 = sb2[0];
    int gidx = base + lrow;
    float w = -1.f; int id = 0x7fffffff;
    if (gidx < ncand) {
        id = cand ? cand[gidx] : gidx;
        int cnt = cand ? ccnt[gidx] : counts[gidx];
        w = (float)cnt / (1.f + expf(-(pv[lrow] + b2)));
    }
    for (int r = 0; r < NTOP; ++r) {
        float bw = w; int bid = id;
#pragma unroll
        for (int m = 1; m < 32; m <<= 1) {
            float ow = __shfl_xor(bw, m); int oid = __shfl_xor(bid, m);
            if (ow > bw || (ow == bw && oid < bid)) { bw = ow; bid = oid; }
        }
        if (w == bw && id == bid) w = -2.f;
        if (lane == r) { taw[blk * NTOP + r] = bw; tai[blk * NTOP + r] = bid; }
    }
}

// ---------- merge candidate blocks' top-10; set validity flag ----------
__global__ __launch_bounds__(256) void k_merge(const float* __restrict__ taw,
                                               const int* __restrict__ tai,
                                               const int* __restrict__ ncand_p,
                                               float* __restrict__ gtw, int* __restrict__ gti,
                                               int* __restrict__ flagp) {
    __shared__ float mw[256 * NTOP];
    __shared__ int   mid[256 * NTOP];
    int t = threadIdx.x;
#pragma unroll
    for (int n = 0; n < NTOP; ++n) { mw[t * NTOP + n] = -1.f; mid[t * NTOP + n] = 0x7fffffff; }
    int nA = *ncand_p; if (nA > CAPA) nA = CAPA;
    int ntA = (nA + 31) / 32;
    for (int i = t; i < ntA * NTOP; i += 256)
        lds_insert(mw, mid, t, taw[i], tai[i]);
    for (int s = 128; s > 0; s >>= 1) {
        __syncthreads();
        if (t < s) {
            const int ta = t * NTOP, tb = (t + s) * NTOP;
            float ow[NTOP]; int oid[NTOP];
            int i = 0, j = 0;
#pragma unroll
            for (int n = 0; n < NTOP; ++n) {
                float wa = mw[ta + i]; int ia = mid[ta + i];
                float wb = mw[tb + j]; int ib = mid[tb + j];
                if (tbetter(wa, ia, wb, ib)) { ow[n] = wa; oid[n] = ia; ++i; }
                else                         { ow[n] = wb; oid[n] = ib; ++j; }
            }
#pragma unroll
            for (int n = 0; n < NTOP; ++n) { mw[ta + n] = ow[n]; mid[ta + n] = oid[n]; }
        }
    }
    __syncthreads();
    if (t < NTOP) { gtw[t] = mw[t]; gti[t] = mid[t]; }
    if (t == 0) *flagp = (mw[NTOP - 1] > (float)(CMIN - 1)) ? 1 : 0;
}

// ---------- final: pick top-10 source + expansion MLP ----------
__global__ __launch_bounds__(512) void k_final(const float* __restrict__ gtw,
                                               const int* __restrict__ gti,
                                               const int* __restrict__ flagp,
                                               const float* __restrict__ tbw,
                                               const int* __restrict__ tbi,
                                               const float* __restrict__ qctx,
                                               const float* __restrict__ emb,
                                               const float* __restrict__ eW1,
                                               const float* __restrict__ eb1,
                                               const float* __restrict__ eW2,
                                               const float* __restrict__ eb2,
                                               float* __restrict__ out) {
    __shared__ float mw[512 * NTOP];
    __shared__ int   mid[512 * NTOP];
    __shared__ int   top_id[NTOP];
    __shared__ float qc[EMBD], em[EMBD], hbuf[HID];
    int t = threadIdx.x;
    int ok = *flagp;
    if (ok) {
        if (t < NTOP) {
            top_id[t] = gti[t];
            out[EMBD + t] = (float)gti[t];
            out[EMBD + NTOP + t] = gtw[t];
        }
    } else {
#pragma unroll
        for (int n = 0; n < NTOP; ++n) { mw[t * NTOP + n] = -1.f; mid[t * NTOP + n] = 0x7fffffff; }
        for (int i = t; i < GRID_F * NTOP; i += 512)
            lds_insert(mw, mid, t, tbw[i], tbi[i]);
        for (int s = 256; s > 0; s >>= 1) {
            __syncthreads();
            if (t < s) {
                const int ta = t * NTOP, tb = (t + s) * NTOP;
                float ow[NTOP]; int oid[NTOP];
                int i = 0, j = 0;
#pragma unroll
                for (int n = 0; n < NTOP; ++n) {
                    float wa = mw[ta + i]; int ia = mid[ta + i];
                    float wb = mw[tb + j]; int ib = mid[tb + j];
                    if (tbetter(wa, ia, wb, ib)) { ow[n] = wa; oid[n] = ia; ++i; }
                    else                         { ow[n] = wb; oid[n] = ib; ++j; }
                }
#pragma unroll
                for (int n = 0; n < NTOP; ++n) { mw[ta + n] = ow[n]; mid[ta + n] = oid[n]; }
            }
        }
        __syncthreads();
        if (t < NTOP) {
            top_id[t] = mid[t];
            out[EMBD + t] = (float)mid[t];
            out[EMBD + NTOP + t] = mw[t];
        }
    }
    __syncthreads();

    for (int i = t; i < EMBD; i += 512) {
        float s = 0.f;
        for (int n = 0; n < NTOP; ++n) s += emb[(long)top_id[n] * EMBD + i];
        em[i] = s * (1.0f / NTOP);
        qc[i] = qctx[i];
    }
    __syncthreads();

    {   // h = relu(feat . eW1 + eb1); 4 threads per col, K split 75
        int col = t >> 2, ks = t & 3;
        float a = 0.f;
        int k0 = ks * 75, k1 = k0 + 75;
        for (int k = k0; k < k1; ++k) {
            float q = qc[k], e = em[k];
            a += q * eW1[(long)k * HID + col];
            a += e * eW1[(long)(EMBD + k) * HID + col];
            a += (q * e) * eW1[(long)(2 * EMBD + k) * HID + col];
        }
        a += __shfl_xor(a, 1);
        a += __shfl_xor(a, 2);
        if (ks == 0) hbuf[col] = fmaxf(a + eb1[col], 0.f);
    }
    __syncthreads();

    for (int i = t; i < EMBD; i += 512) {
        float a = eb2[i];
        for (int j = 0; j < HID; ++j) a += hbuf[j] * eW2[(long)j * EMBD + i];
        out[i] = a;
    }
}

extern "C" void kernel_launch(void* const* d_in, const int* in_sizes, int n_in,
                              void* d_out, int out_size, void* d_ws, size_t ws_size,
                              hipStream_t stream) {
    const int* qterms  = (const int*)d_in[0];
    const int* fdocs   = (const int*)d_in[1];
    const float* emb   = (const float*)d_in[3];
    const float* sW1   = (const float*)d_in[4];
    const float* sb1   = (const float*)d_in[5];
    const float* sW2   = (const float*)d_in[6];
    const float* sb2   = (const float*)d_in[7];
    const float* eW1   = (const float*)d_in[8];
    const float* eb1   = (const float*)d_in[9];
    const float* eW2   = (const float*)d_in[10];
    const float* eb2   = (const float*)d_in[11];
    float* out = (float*)d_out;

    char* ws = (char*)d_ws;
    int*   counts = (int*)ws;                               // 400000 (+4 for ncand)
    int*   ncand  = (int*)(ws + 400000);                    // 4
    float* qctx   = (float*)(ws + 400064);                  // 1200
    float* qcb    = (float*)(ws + 401280);                  // 512
    float* gtw    = (float*)(ws + 401792);                  // 40
    int*   gti    = (int*)(ws + 401856);                    // 40
    int*   flagp  = (int*)(ws + 401920);                    // 4
    int*   cand   = (int*)(ws + 402432);                    // 174764
    int*   ccnt   = (int*)(ws + 577280);                    // 174764
    unsigned short* wfH = (unsigned short*)(ws + 752128);   // 81920
    unsigned short* wfL = (unsigned short*)(ws + 834048);   // 81920
    float* taw    = (float*)(ws + 915968);                  // GRID_A*10*4 = 54640
    int*   tai    = (int*)(ws + 970624);                    // 54640
    float* tbw    = (float*)(ws + 1025280);                 // GRID_F*10*4 = 125000
    int*   tbi    = (int*)(ws + 1150336);                   // 125000 -> 1275336 total

    int nflat = in_sizes[1];
    int hblocks = (nflat + 255) / 256;     // 512

    k_zero<<<(VOCABN + 256) / 256, 256, 0, stream>>>(counts);   // counts + ncand
    k_pre<<<hblocks + 1 + NCHT, 256, 0, stream>>>(qterms, fdocs, nflat, hblocks,
                                                  emb, sW1, sb1, counts, qctx, qcb, wfH, wfL);
    k_compact<<<(VOCABN + 255) / 256, 256, 0, stream>>>(counts, cand, ccnt, ncand);
    // stage A: score candidates only (count >= CMIN)
    k_score<<<GRID_A, 64, 0, stream>>>(emb, wfH, wfL, qcb, sW2, sb2,
                                       counts, cand, ccnt, ncand, (const int*)nullptr, taw, tai);
    k_merge<<<1, 256, 0, stream>>>(taw, tai, ncand, gtw, gti, flagp);
    // exactness fallback: full sweep, early-exits when pruning was valid
    k_score<<<GRID_F, 64, 0, stream>>>(emb, wfH, wfL, qcb, sW2, sb2,
                                       counts, (const int*)nullptr, (const int*)nullptr,
                                       (const int*)nullptr, flagp, tbw, tbi);
    k_final<<<1, 512, 0, stream>>>(gtw, gti, flagp, tbw, tbi,
                                   qctx, emb, eW1, eb1, eW2, eb2, out);
}